// Round 13
// baseline (772.157 us; speedup 1.0000x reference)
//
#include <hip/hip_runtime.h>
#include <math.h>

// ---------------------------------------------------------------------------
// Types
// ---------------------------------------------------------------------------
typedef _Float16 half8 __attribute__((ext_vector_type(8)));
typedef _Float16 half4 __attribute__((ext_vector_type(4)));
typedef __fp16 fp16x2 __attribute__((ext_vector_type(2)));
typedef float f32x4 __attribute__((ext_vector_type(4)));
typedef unsigned uint4v __attribute__((ext_vector_type(4)));

struct FreqT { float f[16]; };

__device__ __forceinline__ f32x4 mfma16(half8 a, half8 b, f32x4 c) {
  return __builtin_amdgcn_mfma_f32_16x16x32_f16(a, b, c, 0, 0, 0);
}

__device__ __forceinline__ void gload_lds16(const void* g, void* l) {
  __builtin_amdgcn_global_load_lds(
      (const __attribute__((address_space(1))) void*)g,
      (__attribute__((address_space(3))) void*)l, 16, 0, 0);
}

__device__ __forceinline__ unsigned pk_f16(float p0, float p1) {
  fp16x2 h = __builtin_amdgcn_cvt_pkrtz(p0, p1);
  return __builtin_bit_cast(unsigned, h);
}

#define S_BARRIER() __builtin_amdgcn_s_barrier()
#define WAIT_LGKM0() asm volatile("s_waitcnt lgkmcnt(0)" ::: "memory")
#define WAIT_LGKM4() asm volatile("s_waitcnt lgkmcnt(4)" ::: "memory")
#define WAIT_LGKM8() asm volatile("s_waitcnt lgkmcnt(8)" ::: "memory")
#define WAIT_VM8() asm volatile("s_waitcnt vmcnt(8)" ::: "memory")
#define WAIT_VM4() asm volatile("s_waitcnt vmcnt(4)" ::: "memory")
#define WAIT_VM0() asm volatile("s_waitcnt vmcnt(0)" ::: "memory")

// ---------------------------------------------------------------------------
// Cast fp32 -> fp16, 8 elems/thread
// ---------------------------------------------------------------------------
__global__ __launch_bounds__(256)
void cast_f32_f16(const float* __restrict__ in, _Float16* __restrict__ out, long n8) {
  long i = (long)blockIdx.x * blockDim.x + threadIdx.x;
  if (i >= n8) return;
  float4 a = ((const float4*)in)[2 * i];
  float4 b = ((const float4*)in)[2 * i + 1];
  half8 v;
  v[0] = (_Float16)a.x; v[1] = (_Float16)a.y; v[2] = (_Float16)a.z; v[3] = (_Float16)a.w;
  v[4] = (_Float16)b.x; v[5] = (_Float16)b.y; v[6] = (_Float16)b.z; v[7] = (_Float16)b.w;
  ((half8*)out)[i] = v;
}

// ---------------------------------------------------------------------------
// GEMM 256x256x64, 8 waves (2M x 4N). m201-style 4-phase-per-K-tile schedule:
// each phase = {ds_read subtile, counted lgkm, 16-MFMA quadrant, barrier};
// stage for t+2 issued after the lgkm0-drained barrier; vmcnt(8) once/tile.
// C = (A @ W^T + bias) * smul.
// ---------------------------------------------------------------------------
#define GBM 256
#define GBN 256
#define GBK 64

template <typename OutT>
__global__ __launch_bounds__(512, 2)
void gemm256(const _Float16* __restrict__ A, const _Float16* __restrict__ W,
             const float* __restrict__ bias, OutT* __restrict__ C,
             int M, int N, int K, float smul) {
  __shared__ __align__(16) _Float16 lds[4][GBM * GBK];

  int nwg = gridDim.x;
  int bid = blockIdx.x;
  int cpx = nwg >> 3;
  int swz = (bid & 7) * cpx + (bid >> 3);
  int ntn = N / GBN;
  int m0 = (swz / ntn) * GBM, n0 = (swz % ntn) * GBN;

  int tid = threadIdx.x, lane = tid & 63, w = tid >> 6;
  int wm = w >> 2, wn = w & 3;
  int g = lane >> 4, lc = lane & 15;

  int r8 = w * 8 + (lane >> 3);
  int cs = (((lane & 7) ^ (lane >> 3)) << 3);
  const _Float16* gA = A + (size_t)(m0 + r8) * K + cs;
  const _Float16* gB = W + (size_t)(n0 + r8) * K + cs;

#define STAGE(bi, k0) do {                                            \
    _Float16* la_ = &lds[(bi) * 2][0] + w * 512;                      \
    _Float16* lb_ = &lds[(bi) * 2 + 1][0] + w * 512;                  \
    _Pragma("unroll")                                                 \
    for (int i_ = 0; i_ < 4; ++i_) {                                  \
      gload_lds16(gA + (size_t)(i_ * 64) * K + (k0), la_ + i_ * 4096);\
      gload_lds16(gB + (size_t)(i_ * 64) * K + (k0), lb_ + i_ * 4096);\
    } } while (0)

  int aOff[8], bOff[4];
#pragma unroll
  for (int mf = 0; mf < 8; ++mf) aOff[mf] = (wm * 128 + mf * 16 + lc) * 64;
#pragma unroll
  for (int nf = 0; nf < 4; ++nf) bOff[nf] = (wn * 64 + nf * 16 + lc) * 64;
  int co0 = ((g ^ (lc & 7)) << 3);
  int co1 = (((4 + g) ^ (lc & 7)) << 3);

  half8 a0[8], a1[8], b0[4], b1[4];
  f32x4 acc[8][4] = {};

#define READ_A0B0(bi) do {                                            \
    const _Float16* lA_ = &lds[(bi) * 2][0];                          \
    const _Float16* lB_ = &lds[(bi) * 2 + 1][0];                      \
    _Pragma("unroll")                                                 \
    for (int mf = 0; mf < 4; ++mf) {                                  \
      a0[mf * 2 + 0] = *(const half8*)&lA_[aOff[mf] + co0];           \
      a0[mf * 2 + 1] = *(const half8*)&lA_[aOff[mf] + co1];           \
    }                                                                 \
    _Pragma("unroll")                                                 \
    for (int nf = 0; nf < 2; ++nf) {                                  \
      b0[nf * 2 + 0] = *(const half8*)&lB_[bOff[nf] + co0];           \
      b0[nf * 2 + 1] = *(const half8*)&lB_[bOff[nf] + co1];           \
    } } while (0)

#define READ_B1(bi) do {                                              \
    const _Float16* lB_ = &lds[(bi) * 2 + 1][0];                      \
    _Pragma("unroll")                                                 \
    for (int nf = 0; nf < 2; ++nf) {                                  \
      b1[nf * 2 + 0] = *(const half8*)&lB_[bOff[nf + 2] + co0];       \
      b1[nf * 2 + 1] = *(const half8*)&lB_[bOff[nf + 2] + co1];       \
    } } while (0)

#define READ_A1(bi) do {                                              \
    const _Float16* lA_ = &lds[(bi) * 2][0];                          \
    _Pragma("unroll")                                                 \
    for (int mf = 0; mf < 4; ++mf) {                                  \
      a1[mf * 2 + 0] = *(const half8*)&lA_[aOff[mf + 4] + co0];       \
      a1[mf * 2 + 1] = *(const half8*)&lA_[aOff[mf + 4] + co1];       \
    } } while (0)

#define MFMA_Q(mq, nq, ar, br) do {                                   \
    __builtin_amdgcn_s_setprio(1);                                    \
    _Pragma("unroll")                                                 \
    for (int mf = 0; mf < 4; ++mf)                                    \
      _Pragma("unroll")                                               \
      for (int nf = 0; nf < 2; ++nf)                                  \
        _Pragma("unroll")                                             \
        for (int kk = 0; kk < 2; ++kk)                                \
          acc[(mq) * 4 + mf][(nq) * 2 + nf] =                         \
              mfma16(ar[mf * 2 + kk], br[nf * 2 + kk],                \
                     acc[(mq) * 4 + mf][(nq) * 2 + nf]);              \
    __builtin_amdgcn_s_setprio(0); } while (0)

  const int NT = K >> 6;  // >= 3

  // prologue: tiles 0,1 in flight; wait tile 0; issue its A0/B0 reads
  STAGE(0, 0);
  STAGE(1, GBK);
  WAIT_VM8();
  S_BARRIER();
  READ_A0B0(0);

  for (int t = 0; t < NT - 2; ++t) {
    int cur = t & 1;
    // P1: quadrant (0,0); issue B1 reads
    READ_B1(cur);
    WAIT_LGKM4();                  // A0,B0 resident (B1's 4 may be in flight)
    MFMA_Q(0, 0, a0, b0);
    S_BARRIER();
    // P2: quadrant (0,1); issue A1 reads
    READ_A1(cur);
    WAIT_LGKM8();                  // B1 resident (A1's 8 may be in flight)
    MFMA_Q(0, 1, a0, b1);
    S_BARRIER();
    // P3: quadrant (1,1); all buf[cur] reads drained -> free to stage t+2
    WAIT_LGKM0();
    MFMA_Q(1, 1, a1, b1);
    S_BARRIER();                   // block-wide: buf[cur] fully consumed
    STAGE(cur, (t + 2) << 6);
    // P4: quadrant (1,0); retire t+1's loads (t+2's 8 stay in flight)
    MFMA_Q(1, 0, a1, b0);
    WAIT_VM8();
    S_BARRIER();
    READ_A0B0(cur ^ 1);
  }
  {  // t = NT-2: no more staging
    int cur = (NT - 2) & 1;
    READ_B1(cur);
    WAIT_LGKM4();
    MFMA_Q(0, 0, a0, b0);
    S_BARRIER();
    READ_A1(cur);
    WAIT_LGKM8();
    MFMA_Q(0, 1, a0, b1);
    S_BARRIER();
    WAIT_LGKM0();
    MFMA_Q(1, 1, a1, b1);
    MFMA_Q(1, 0, a1, b0);
    WAIT_VM0();                    // last tile resident
    S_BARRIER();
    READ_A0B0(cur ^ 1);
  }
  {  // t = NT-1
    int cur = (NT - 1) & 1;
    READ_B1(cur);
    READ_A1(cur);
    WAIT_LGKM0();
    MFMA_Q(0, 0, a0, b0);
    MFMA_Q(0, 1, a0, b1);
    MFMA_Q(1, 1, a1, b1);
    MFMA_Q(1, 0, a1, b0);
  }

  int crow = m0 + wm * 128 + g * 4;
  int ccol = n0 + wn * 64 + lc;
#pragma unroll
  for (int nf = 0; nf < 4; ++nf) {
    float bv = bias[ccol + nf * 16];
#pragma unroll
    for (int mf = 0; mf < 8; ++mf)
#pragma unroll
      for (int j = 0; j < 4; ++j)
        C[(size_t)(crow + mf * 16 + j) * N + ccol + nf * 16] =
            (OutT)((acc[mf][nf][j] + bv) * smul);
  }
#undef STAGE
#undef READ_A0B0
#undef READ_B1
#undef READ_A1
#undef MFMA_Q
}

// ---------------------------------------------------------------------------
// RoPE (faithful fp32 overflow-to-zero freqs, dim=n_heads)
// ---------------------------------------------------------------------------
__global__ __launch_bounds__(256)
void rope_kernel(_Float16* __restrict__ x, FreqT ft, int Sn, int E, long n8) {
  long i = (long)blockIdx.x * blockDim.x + threadIdx.x;
  if (i >= n8) return;
  int epr = E / 8;
  int e8 = (int)(i % epr);
  int s = (int)((i / epr) % Sn);
  int fj = e8 & 15;
  float fr = ft.f[fj];
  float ang = (float)s * fr;
  float sv, cv;
  sincosf(ang, &sv, &cv);
  half8 v = ((const half8*)x)[i];
  half8 o;
#pragma unroll
  for (int p = 0; p < 4; ++p) {
    float x1 = (float)v[2 * p], x2 = (float)v[2 * p + 1];
    o[2 * p] = (_Float16)(x1 * cv - x2 * sv);
    o[2 * p + 1] = (_Float16)(x1 * sv + x2 * cv);
  }
  ((half8*)x)[i] = o;
}

// ---------------------------------------------------------------------------
// V transpose: vh [B,S,H*D] -> vt [B,H,D,S]
// ---------------------------------------------------------------------------
__global__ __launch_bounds__(256)
void transpose_v(const _Float16* __restrict__ v, _Float16* __restrict__ vt,
                 int Hn, int Sn) {
  const int D = 128;
  const int E = Hn * D;
  __shared__ _Float16 t[64][130];
  int spb = Sn / 64;
  int bid = blockIdx.x;
  int s0 = (bid % spb) * 64;
  int bh = bid / spb;
  int b = bh / Hn, h = bh % Hn;
  int tid = threadIdx.x;
  int r = tid >> 2, dc = (tid & 3) * 32;
  const _Float16* src = v + (size_t)(b * Sn + s0 + r) * E + h * D + dc;
#pragma unroll
  for (int i = 0; i < 4; ++i) {
    half8 x = *(const half8*)(src + i * 8);
#pragma unroll
    for (int k = 0; k < 4; ++k) {
      _Float16 a0 = x[2 * k], a1 = x[2 * k + 1];
      t[r][dc + i * 8 + 2 * k] = a0;
      t[r][dc + i * 8 + 2 * k + 1] = a1;
    }
  }
  __syncthreads();
  int d = tid >> 1, sh = (tid & 1) * 32;
  half8 ov[4];
#pragma unroll
  for (int c = 0; c < 4; ++c)
#pragma unroll
    for (int j = 0; j < 8; ++j)
      ov[c][j] = t[sh + c * 8 + j][d];
  _Float16* dst = vt + ((size_t)bh * D + d) * Sn + s0 + sh;
#pragma unroll
  for (int c = 0; c < 4; ++c)
    *(half8*)(dst + c * 8) = ov[c];
}

// ---------------------------------------------------------------------------
// Flash attention (non-causal), D=128, 4 waves, QB=128 (32 q/wave), KB=64.
// Q pre-scaled by scale*log2e in its GEMM epilogue -> softmax runs in
// exp2 domain (v_exp_f32 directly, no per-element muls). Swapped QK^T;
// P in registers (cvt_pkrtz + permlane, named scalars). K and V
// double-buffered, counted-vmcnt pipeline (no drain in steady loop).
// ---------------------------------------------------------------------------
#define QB 128
#define KB 64
#define THR2 11.541561f  // 8 * log2(e)

__global__ __launch_bounds__(256, 2)
void flash_attn(const _Float16* __restrict__ qg, const _Float16* __restrict__ kg,
                const _Float16* __restrict__ vt, _Float16* __restrict__ og,
                int Bn, int Hn, int Sn) {
  const int D = 128;
  const int E = Hn * D;

  __shared__ _Float16 Ksh[2][KB * 128];   // swizzled, 2 x 16KB
  __shared__ _Float16 Vsh[2][D * KB];     // V^T tiles, swizzled, 2 x 16KB
  __shared__ float sm[4][32];             // per-wave stat broadcast

  int qtiles = Sn / QB;                   // 16
  int nwg = gridDim.x;
  int bid = blockIdx.x;
  int swzb = (bid & 7) * (nwg >> 3) + (bid >> 3);  // XCD-grouped
  int bh = swzb / qtiles, qt = swzb % qtiles;
  int b = bh / Hn, h = bh % Hn;

  int tid = threadIdx.x, lane = tid & 63, w = tid >> 6;
  int g = lane >> 4, lc = lane & 15;
  int lc7 = lc & 7;

  const size_t headoff = ((size_t)b * Sn) * E + (size_t)h * D;
  const _Float16* qp = qg + headoff;
  const _Float16* kp = kg + headoff;
  const _Float16* vtp = vt + (size_t)(b * Hn + h) * D * Sn;  // [d][s]

  // Q fragments (B-operand: Q[q=mf*16+lc][k]) — already scaled by s*log2e
  int q0 = qt * QB + w * 32;
  half8 aq[2][4];
#pragma unroll
  for (int mf = 0; mf < 2; ++mf)
#pragma unroll
    for (int kf = 0; kf < 4; ++kf)
      aq[mf][kf] = *(const half8*)(qp + (size_t)(q0 + mf * 16 + lc) * E + kf * 32 + g * 8);

  float mrun[2] = {-1e30f, -1e30f}, lpart[2] = {0.f, 0.f};
  f32x4 o[2][8] = {};

  // K staging: 4 rows/call, pre-swizzled source col
  int krow = 4 * w + (lane >> 4);
  int kcol = ((lane & 15) ^ (krow & 7)) * 8;
  const _Float16* gK = kp + (size_t)krow * E + kcol;
  // V^T staging: 8 rows/call, pre-swizzled source col
  int vrow = w * 32 + (lane >> 3);
  int vcol = ((lane & 7) ^ (vrow & 7)) * 8;
  const _Float16* gV = vtp + (size_t)vrow * Sn + vcol;

  float* smw = sm[w];

  const int NT = Sn / KB;

#define STAGE_K(buf, kt) do {                                          \
    _Float16* lK_ = Ksh[buf] + w * 512;                                \
    _Pragma("unroll")                                                  \
    for (int i_ = 0; i_ < 4; ++i_)                                     \
      gload_lds16(gK + (size_t)((kt) * KB + 16 * i_) * E, lK_ + i_ * 2048); \
  } while (0)
#define STAGE_V(buf, kt) do {                                          \
    _Float16* lV_ = Vsh[buf] + w * 2048;                               \
    _Pragma("unroll")                                                  \
    for (int p_ = 0; p_ < 4; ++p_)                                     \
      gload_lds16(gV + (size_t)(p_ * 8) * Sn + (kt) * KB, lV_ + p_ * 512); \
  } while (0)

  // prologue: K(0), K(1), V(0) in flight; wait only K(0)
  STAGE_K(0, 0);
  STAGE_K(1, 1);
  STAGE_V(0, 0);
  WAIT_VM8();
  S_BARRIER();

  for (int t = 0; t < NT; ++t) {
    int c = t & 1;

    // [B1] QK^T swapped on Ksh[c]: per lane q = mf*16+lc, kv = nf*16+g*4+j
    f32x4 st[2][4] = {};
    {
      const _Float16* Kc = Ksh[c];
      __builtin_amdgcn_s_setprio(1);
#pragma unroll
      for (int kf = 0; kf < 4; ++kf) {
        half8 bk[4];
#pragma unroll
        for (int nf = 0; nf < 4; ++nf)
          bk[nf] = *(const half8*)&Kc[(nf * 16 + lc) * 128 + (((kf * 4 + g) ^ lc7) << 3)];
#pragma unroll
        for (int nf = 0; nf < 4; ++nf)
#pragma unroll
          for (int mf = 0; mf < 2; ++mf)
            st[mf][nf] = mfma16(bk[nf], aq[mf][kf], st[mf][nf]);
      }
      __builtin_amdgcn_s_setprio(0);
    }
    WAIT_LGKM0();
    S_BARRIER();  // all waves done reading Ksh[c] (and prior PV's Vsh)

    // issue next-tile stages into just-freed buffers (stay in flight)
    if (t + 1 < NT) STAGE_V(c ^ 1, t + 1);
    if (t + 2 < NT) STAGE_K(c, t + 2);

    // softmax in exp2 domain (st already includes scale*log2e), defer-max
    bool resc[2];
#pragma unroll
    for (int mf = 0; mf < 2; ++mf) {
      f32x4 m4 = st[mf][0];
#pragma unroll
      for (int nf = 1; nf < 4; ++nf)
#pragma unroll
        for (int j = 0; j < 4; ++j) m4[j] = fmaxf(m4[j], st[mf][nf][j]);
      float mx = fmaxf(fmaxf(m4[0], m4[1]), fmaxf(m4[2], m4[3]));
      mx = fmaxf(mx, __shfl_xor(mx, 16));
      mx = fmaxf(mx, __shfl_xor(mx, 32));
      resc[mf] = __any(mx > mrun[mf] + THR2);
      if (resc[mf]) {
        float mnew = fmaxf(mrun[mf], mx);
        float r = __builtin_amdgcn_exp2f(mrun[mf] - mnew);
        mrun[mf] = mnew;
        lpart[mf] *= r;
        if (g == 0) smw[mf * 16 + lc] = r;
      }
    }
#pragma unroll
    for (int mf = 0; mf < 2; ++mf)
      if (resc[mf]) {
        f32x4 rv = *(const f32x4*)&smw[mf * 16 + g * 4];
#pragma unroll
        for (int df = 0; df < 8; ++df)
#pragma unroll
          for (int j = 0; j < 4; ++j) o[mf][df][j] *= rv[j];
      }

    // P = exp2(st - m), pack + permlane dance. Named scalars only.
    half8 pa00, pa01, pa10, pa11;  // pa<mf><kk>
#define PACK_P(MF, PA0, PA1) do {                                          \
      float e0, e1;                                                        \
      e0 = __builtin_amdgcn_exp2f(st[MF][0][0] - mrun[MF]);                \
      e1 = __builtin_amdgcn_exp2f(st[MF][0][1] - mrun[MF]);                \
      lpart[MF] += e0 + e1; unsigned k00 = pk_f16(e0, e1);                 \
      e0 = __builtin_amdgcn_exp2f(st[MF][0][2] - mrun[MF]);                \
      e1 = __builtin_amdgcn_exp2f(st[MF][0][3] - mrun[MF]);                \
      lpart[MF] += e0 + e1; unsigned k01 = pk_f16(e0, e1);                 \
      e0 = __builtin_amdgcn_exp2f(st[MF][1][0] - mrun[MF]);                \
      e1 = __builtin_amdgcn_exp2f(st[MF][1][1] - mrun[MF]);                \
      lpart[MF] += e0 + e1; unsigned k10 = pk_f16(e0, e1);                 \
      e0 = __builtin_amdgcn_exp2f(st[MF][1][2] - mrun[MF]);                \
      e1 = __builtin_amdgcn_exp2f(st[MF][1][3] - mrun[MF]);                \
      lpart[MF] += e0 + e1; unsigned k11 = pk_f16(e0, e1);                 \
      e0 = __builtin_amdgcn_exp2f(st[MF][2][0] - mrun[MF]);                \
      e1 = __builtin_amdgcn_exp2f(st[MF][2][1] - mrun[MF]);                \
      lpart[MF] += e0 + e1; unsigned k20 = pk_f16(e0, e1);                 \
      e0 = __builtin_amdgcn_exp2f(st[MF][2][2] - mrun[MF]);                \
      e1 = __builtin_amdgcn_exp2f(st[MF][2][3] - mrun[MF]);                \
      lpart[MF] += e0 + e1; unsigned k21 = pk_f16(e0, e1);                 \
      e0 = __builtin_amdgcn_exp2f(st[MF][3][0] - mrun[MF]);                \
      e1 = __builtin_amdgcn_exp2f(st[MF][3][1] - mrun[MF]);                \
      lpart[MF] += e0 + e1; unsigned k30 = pk_f16(e0, e1);                 \
      e0 = __builtin_amdgcn_exp2f(st[MF][3][2] - mrun[MF]);                \
      e1 = __builtin_amdgcn_exp2f(st[MF][3][3] - mrun[MF]);                \
      lpart[MF] += e0 + e1; unsigned k31 = pk_f16(e0, e1);                 \
      asm("v_permlane32_swap_b32 %0, %1" : "+v"(k00), "+v"(k10));          \
      asm("v_permlane16_swap_b32 %0, %1" : "+v"(k00), "+v"(k10));          \
      asm("v_permlane32_swap_b32 %0, %1" : "+v"(k01), "+v"(k11));          \
      asm("v_permlane16_swap_b32 %0, %1" : "+v"(k01), "+v"(k11));          \
      asm("v_permlane32_swap_b32 %0, %1" : "+v"(k20), "+v"(k30));          \
      asm("v_permlane16_swap_b32 %0, %1" : "+v"(k20), "+v"(k30));          \
      asm("v_permlane32_swap_b32 %0, %1" : "+v"(k21), "+v"(k31));          \
      asm("v_permlane16_swap_b32 %0, %1" : "+v"(k21), "+v"(k31));          \
      uint4v p0v, p1v;                                                     \
      p0v[0] = k00; p0v[1] = k01; p0v[2] = k10; p0v[3] = k11;              \
      p1v[0] = k20; p1v[1] = k21; p1v[2] = k30; p1v[3] = k31;              \
      PA0 = __builtin_bit_cast(half8, p0v);                                \
      PA1 = __builtin_bit_cast(half8, p1v);                                \
    } while (0)
    PACK_P(0, pa00, pa01);
    PACK_P(1, pa10, pa11);
#undef PACK_P

    // retire exactly V(t) + K(t+1); newer stages stay in flight
    if (t + 2 < NT) { WAIT_VM8(); }
    else if (t + 1 < NT) { WAIT_VM4(); }
    else { WAIT_VM0(); }
    S_BARRIER();  // all waves' V(t) landed

    // PV: O[32,128] += P[32,64] @ V[64,128]  (P from registers)
    __builtin_amdgcn_s_setprio(1);
    {
      const _Float16* Vc = Vsh[c];
      int csw0 = (g ^ lc7) << 3;
      int csw1 = ((4 + g) ^ lc7) << 3;
#pragma unroll
      for (int df = 0; df < 8; ++df) {
        half8 bv0 = *(const half8*)&Vc[(df * 16 + lc) * 64 + csw0];
        o[0][df] = mfma16(pa00, bv0, o[0][df]);
        o[1][df] = mfma16(pa10, bv0, o[1][df]);
      }
#pragma unroll
      for (int df = 0; df < 8; ++df) {
        half8 bv1 = *(const half8*)&Vc[(df * 16 + lc) * 64 + csw1];
        o[0][df] = mfma16(pa01, bv1, o[0][df]);
        o[1][df] = mfma16(pa11, bv1, o[1][df]);
      }
    }
    __builtin_amdgcn_s_setprio(0);
  }
#undef STAGE_K
#undef STAGE_V

  // epilogue: final l across g-groups, broadcast 1/l, normalize, write
#pragma unroll
  for (int mf = 0; mf < 2; ++mf) {
    float l = lpart[mf];
    l += __shfl_xor(l, 16);
    l += __shfl_xor(l, 32);
    if (g == 0) smw[mf * 16 + lc] = 1.0f / l;
  }
  _Float16* op = og + headoff;
#pragma unroll
  for (int mf = 0; mf < 2; ++mf) {
    f32x4 li = *(const f32x4*)&smw[mf * 16 + g * 4];
#pragma unroll
    for (int j = 0; j < 4; ++j) {
      int row = q0 + mf * 16 + g * 4 + j;
#pragma unroll
      for (int df = 0; df < 8; ++df)
        op[(size_t)row * E + df * 16 + lc] = (_Float16)(o[mf][df][j] * li[j]);
    }
  }
}

// ---------------------------------------------------------------------------
// Launch
// ---------------------------------------------------------------------------
extern "C" void kernel_launch(void* const* d_in, const int* in_sizes, int n_in,
                              void* d_out, int out_size, void* d_ws, size_t ws_size,
                              hipStream_t stream) {
  const float* x  = (const float*)d_in[0];
  const float* Wq = (const float*)d_in[1];
  const float* bq = (const float*)d_in[2];
  const float* Wk = (const float*)d_in[3];
  const float* bk = (const float*)d_in[4];
  const float* Wv = (const float*)d_in[5];
  const float* bv = (const float*)d_in[6];
  const float* Wo = (const float*)d_in[7];
  const float* bo = (const float*)d_in[8];

  const int E = in_sizes[2];        // 4096
  const int M = in_sizes[0] / E;    // B*S = 4096
  const int S = 2048;
  const int Bb = M / S;             // 2
  const int H = 32;

  _Float16* xh = (_Float16*)d_ws;               // M*E (reused as attn-out)
  _Float16* wh = xh + (size_t)M * E;            // E*E (W casts; then V^T)
  _Float16* qh = wh + (size_t)E * E;            // M*E
  _Float16* kh = qh + (size_t)M * E;
  _Float16* vh = kh + (size_t)M * E;
  _Float16* oh = xh;
  _Float16* vtb = wh;                           // V^T lives in wh during attn

  FreqT ft;
  for (int j = 0; j < 16; ++j) {
    float pf = (float)pow(10000.0, (double)(2 * j));  // inf for j>=5 (faithful)
    ft.f[j] = 1.0f / (pf / 32.0f);
  }

  // Q pre-scale: 1/sqrt(128) * log2(e)  (softmax runs in exp2 domain)
  const float qs = 0.08838834764831845f * 1.4426950408889634f;

  long nx8 = (long)M * E / 8;
  long nw8 = (long)E * E / 8;
  dim3 blk(256);
  int cb_x = (int)((nx8 + 255) / 256);
  int cb_w = (int)((nw8 + 255) / 256);
  int gemm_grid = (M / GBM) * (E / GBN);  // 256

  cast_f32_f16<<<cb_x, blk, 0, stream>>>(x, xh, nx8);

  cast_f32_f16<<<cb_w, blk, 0, stream>>>(Wq, wh, nw8);
  gemm256<_Float16><<<gemm_grid, 512, 0, stream>>>(xh, wh, bq, qh, M, E, E, qs);
  cast_f32_f16<<<cb_w, blk, 0, stream>>>(Wk, wh, nw8);
  gemm256<_Float16><<<gemm_grid, 512, 0, stream>>>(xh, wh, bk, kh, M, E, E, 1.0f);
  cast_f32_f16<<<cb_w, blk, 0, stream>>>(Wv, wh, nw8);
  gemm256<_Float16><<<gemm_grid, 512, 0, stream>>>(xh, wh, bv, vh, M, E, E, 1.0f);

  rope_kernel<<<cb_x, blk, 0, stream>>>(qh, ft, S, E, nx8);
  rope_kernel<<<cb_x, blk, 0, stream>>>(kh, ft, S, E, nx8);

  transpose_v<<<Bb * H * (S / 64), blk, 0, stream>>>(vh, vtb, H, S);

  flash_attn<<<Bb * H * (S / QB), blk, 0, stream>>>(qh, kh, vtb, oh, Bb, H, S);

  cast_f32_f16<<<cb_w, blk, 0, stream>>>(Wo, wh, nw8);
  gemm256<float><<<gemm_grid, 512, 0, stream>>>(oh, wh, bo, (float*)d_out, M, E, E, 1.0f);
}

// Round 14
// 766.784 us; speedup vs baseline: 1.0070x; 1.0070x over previous
//
#include <hip/hip_runtime.h>
#include <math.h>

// ---------------------------------------------------------------------------
// Types
// ---------------------------------------------------------------------------
typedef _Float16 half8 __attribute__((ext_vector_type(8)));
typedef _Float16 half4 __attribute__((ext_vector_type(4)));
typedef __fp16 fp16x2 __attribute__((ext_vector_type(2)));
typedef float f32x4 __attribute__((ext_vector_type(4)));
typedef unsigned uint4v __attribute__((ext_vector_type(4)));

struct FreqT { float f[16]; };

__device__ __forceinline__ f32x4 mfma16(half8 a, half8 b, f32x4 c) {
  return __builtin_amdgcn_mfma_f32_16x16x32_f16(a, b, c, 0, 0, 0);
}

__device__ __forceinline__ void gload_lds16(const void* g, void* l) {
  __builtin_amdgcn_global_load_lds(
      (const __attribute__((address_space(1))) void*)g,
      (__attribute__((address_space(3))) void*)l, 16, 0, 0);
}

__device__ __forceinline__ unsigned pk_f16(float p0, float p1) {
  fp16x2 h = __builtin_amdgcn_cvt_pkrtz(p0, p1);
  return __builtin_bit_cast(unsigned, h);
}

#define S_BARRIER() __builtin_amdgcn_s_barrier()
#define WAIT_LGKM0() asm volatile("s_waitcnt lgkmcnt(0)" ::: "memory")
#define WAIT_VM8() asm volatile("s_waitcnt vmcnt(8)" ::: "memory")
#define WAIT_VM4() asm volatile("s_waitcnt vmcnt(4)" ::: "memory")
#define WAIT_VM0() asm volatile("s_waitcnt vmcnt(0)" ::: "memory")

// ---------------------------------------------------------------------------
// Cast fp32 -> fp16, 8 elems/thread
// ---------------------------------------------------------------------------
__global__ __launch_bounds__(256)
void cast_f32_f16(const float* __restrict__ in, _Float16* __restrict__ out, long n8) {
  long i = (long)blockIdx.x * blockDim.x + threadIdx.x;
  if (i >= n8) return;
  float4 a = ((const float4*)in)[2 * i];
  float4 b = ((const float4*)in)[2 * i + 1];
  half8 v;
  v[0] = (_Float16)a.x; v[1] = (_Float16)a.y; v[2] = (_Float16)a.z; v[3] = (_Float16)a.w;
  v[4] = (_Float16)b.x; v[5] = (_Float16)b.y; v[6] = (_Float16)b.z; v[7] = (_Float16)b.w;
  ((half8*)out)[i] = v;
}

// ---------------------------------------------------------------------------
// GEMM 256x256x64, 8 waves (2M x 4N), r12's 2-phase counted-vmcnt pipeline.
// C = (A @ W^T + bias) * smul.
// ---------------------------------------------------------------------------
#define GBM 256
#define GBN 256
#define GBK 64

template <typename OutT>
__global__ __launch_bounds__(512, 2)
void gemm256(const _Float16* __restrict__ A, const _Float16* __restrict__ W,
             const float* __restrict__ bias, OutT* __restrict__ C,
             int M, int N, int K, float smul) {
  __shared__ __align__(16) _Float16 lds[4][GBM * GBK];

  int nwg = gridDim.x;
  int bid = blockIdx.x;
  int cpx = nwg >> 3;
  int swz = (bid & 7) * cpx + (bid >> 3);
  int ntn = N / GBN;
  int m0 = (swz / ntn) * GBM, n0 = (swz % ntn) * GBN;

  int tid = threadIdx.x, lane = tid & 63, w = tid >> 6;
  int wm = w >> 2, wn = w & 3;
  int g = lane >> 4, lc = lane & 15;

  int r8 = w * 8 + (lane >> 3);
  int cs = (((lane & 7) ^ (lane >> 3)) << 3);
  const _Float16* gA = A + (size_t)(m0 + r8) * K + cs;
  const _Float16* gB = W + (size_t)(n0 + r8) * K + cs;

#define STAGE(bi, k0) do {                                            \
    _Float16* la_ = &lds[(bi) * 2][0] + w * 512;                      \
    _Float16* lb_ = &lds[(bi) * 2 + 1][0] + w * 512;                  \
    _Pragma("unroll")                                                 \
    for (int i_ = 0; i_ < 4; ++i_) {                                  \
      gload_lds16(gA + (size_t)(i_ * 64) * K + (k0), la_ + i_ * 4096);\
      gload_lds16(gB + (size_t)(i_ * 64) * K + (k0), lb_ + i_ * 4096);\
    } } while (0)

  int aOff[8], bOff[4];
#pragma unroll
  for (int mf = 0; mf < 8; ++mf) aOff[mf] = (wm * 128 + mf * 16 + lc) * 64;
#pragma unroll
  for (int nf = 0; nf < 4; ++nf) bOff[nf] = (wn * 64 + nf * 16 + lc) * 64;
  int co0 = ((g ^ (lc & 7)) << 3);
  int co1 = (((4 + g) ^ (lc & 7)) << 3);

  half8 a0[8], a1[8], b0[4], b1[4];
  f32x4 acc[8][4] = {};

#define LOAD_SET0(bi) do {                                            \
    const _Float16* lA_ = &lds[(bi) * 2][0];                          \
    const _Float16* lB_ = &lds[(bi) * 2 + 1][0];                      \
    _Pragma("unroll")                                                 \
    for (int mf = 0; mf < 4; ++mf) {                                  \
      a0[mf * 2 + 0] = *(const half8*)&lA_[aOff[mf] + co0];           \
      a0[mf * 2 + 1] = *(const half8*)&lA_[aOff[mf] + co1];           \
    }                                                                 \
    _Pragma("unroll")                                                 \
    for (int nf = 0; nf < 2; ++nf) {                                  \
      b0[nf * 2 + 0] = *(const half8*)&lB_[bOff[nf] + co0];           \
      b0[nf * 2 + 1] = *(const half8*)&lB_[bOff[nf] + co1];           \
    } } while (0)

#define LOAD_SET1(bi) do {                                            \
    const _Float16* lA_ = &lds[(bi) * 2][0];                          \
    const _Float16* lB_ = &lds[(bi) * 2 + 1][0];                      \
    _Pragma("unroll")                                                 \
    for (int mf = 0; mf < 4; ++mf) {                                  \
      a1[mf * 2 + 0] = *(const half8*)&lA_[aOff[mf + 4] + co0];       \
      a1[mf * 2 + 1] = *(const half8*)&lA_[aOff[mf + 4] + co1];       \
    }                                                                 \
    _Pragma("unroll")                                                 \
    for (int nf = 0; nf < 2; ++nf) {                                  \
      b1[nf * 2 + 0] = *(const half8*)&lB_[bOff[nf + 2] + co0];       \
      b1[nf * 2 + 1] = *(const half8*)&lB_[bOff[nf + 2] + co1];       \
    } } while (0)

#define MFMA_Q(mq, nq, ar, br) do {                                   \
    __builtin_amdgcn_s_setprio(1);                                    \
    _Pragma("unroll")                                                 \
    for (int mf = 0; mf < 4; ++mf)                                    \
      _Pragma("unroll")                                               \
      for (int nf = 0; nf < 2; ++nf)                                  \
        _Pragma("unroll")                                             \
        for (int kk = 0; kk < 2; ++kk)                                \
          acc[(mq) * 4 + mf][(nq) * 2 + nf] =                         \
              mfma16(ar[mf * 2 + kk], br[nf * 2 + kk],                \
                     acc[(mq) * 4 + mf][(nq) * 2 + nf]);              \
    __builtin_amdgcn_s_setprio(0); } while (0)

  const int NT = K >> 6;

  STAGE(0, 0);
  STAGE(1, GBK);
  WAIT_VM8();
  S_BARRIER();
  LOAD_SET0(0);

  for (int t = 0; t < NT - 2; ++t) {
    int cur = t & 1;
    LOAD_SET1(cur);
    MFMA_Q(0, 0, a0, b0);
    MFMA_Q(0, 1, a0, b1);
    WAIT_LGKM0();
    S_BARRIER();
    STAGE(cur, (t + 2) << 6);
    MFMA_Q(1, 1, a1, b1);
    MFMA_Q(1, 0, a1, b0);
    WAIT_VM8();
    S_BARRIER();
    LOAD_SET0(cur ^ 1);
  }
  {
    int cur = (NT - 2) & 1;
    LOAD_SET1(cur);
    MFMA_Q(0, 0, a0, b0);
    MFMA_Q(0, 1, a0, b1);
    MFMA_Q(1, 1, a1, b1);
    MFMA_Q(1, 0, a1, b0);
    WAIT_VM0();
    S_BARRIER();
    LOAD_SET0(cur ^ 1);
  }
  {
    LOAD_SET1((NT - 1) & 1);
    MFMA_Q(0, 0, a0, b0);
    MFMA_Q(0, 1, a0, b1);
    MFMA_Q(1, 1, a1, b1);
    MFMA_Q(1, 0, a1, b0);
  }

  int crow = m0 + wm * 128 + g * 4;
  int ccol = n0 + wn * 64 + lc;
#pragma unroll
  for (int nf = 0; nf < 4; ++nf) {
    float bv = bias[ccol + nf * 16];
#pragma unroll
    for (int mf = 0; mf < 8; ++mf)
#pragma unroll
      for (int j = 0; j < 4; ++j)
        C[(size_t)(crow + mf * 16 + j) * N + ccol + nf * 16] =
            (OutT)((acc[mf][nf][j] + bv) * smul);
  }
#undef STAGE
#undef LOAD_SET0
#undef LOAD_SET1
#undef MFMA_Q
}

// ---------------------------------------------------------------------------
// RoPE (faithful fp32 overflow-to-zero freqs, dim=n_heads) — used for K only
// ---------------------------------------------------------------------------
__global__ __launch_bounds__(256)
void rope_kernel(_Float16* __restrict__ x, FreqT ft, int Sn, int E, long n8) {
  long i = (long)blockIdx.x * blockDim.x + threadIdx.x;
  if (i >= n8) return;
  int epr = E / 8;
  int e8 = (int)(i % epr);
  int s = (int)((i / epr) % Sn);
  int fj = e8 & 15;
  float fr = ft.f[fj];
  float ang = (float)s * fr;
  float sv, cv;
  sincosf(ang, &sv, &cv);
  half8 v = ((const half8*)x)[i];
  half8 o;
#pragma unroll
  for (int p = 0; p < 4; ++p) {
    float x1 = (float)v[2 * p], x2 = (float)v[2 * p + 1];
    o[2 * p] = (_Float16)(x1 * cv - x2 * sv);
    o[2 * p + 1] = (_Float16)(x1 * sv + x2 * cv);
  }
  ((half8*)x)[i] = o;
}

// ---------------------------------------------------------------------------
// V transpose: vh [B,S,H*D] -> vt [B,H,D,S]
// ---------------------------------------------------------------------------
__global__ __launch_bounds__(256)
void transpose_v(const _Float16* __restrict__ v, _Float16* __restrict__ vt,
                 int Hn, int Sn) {
  const int D = 128;
  const int E = Hn * D;
  __shared__ _Float16 t[64][130];
  int spb = Sn / 64;
  int bid = blockIdx.x;
  int s0 = (bid % spb) * 64;
  int bh = bid / spb;
  int b = bh / Hn, h = bh % Hn;
  int tid = threadIdx.x;
  int r = tid >> 2, dc = (tid & 3) * 32;
  const _Float16* src = v + (size_t)(b * Sn + s0 + r) * E + h * D + dc;
#pragma unroll
  for (int i = 0; i < 4; ++i) {
    half8 x = *(const half8*)(src + i * 8);
#pragma unroll
    for (int k = 0; k < 4; ++k) {
      _Float16 a0 = x[2 * k], a1 = x[2 * k + 1];
      t[r][dc + i * 8 + 2 * k] = a0;
      t[r][dc + i * 8 + 2 * k + 1] = a1;
    }
  }
  __syncthreads();
  int d = tid >> 1, sh = (tid & 1) * 32;
  half8 ov[4];
#pragma unroll
  for (int c = 0; c < 4; ++c)
#pragma unroll
    for (int j = 0; j < 8; ++j)
      ov[c][j] = t[sh + c * 8 + j][d];
  _Float16* dst = vt + ((size_t)bh * D + d) * Sn + s0 + sh;
#pragma unroll
  for (int c = 0; c < 4; ++c)
    *(half8*)(dst + c * 8) = ov[c];
}

// ---------------------------------------------------------------------------
// Flash attention (non-causal), D=128, 4 waves, QB=128 (32 q/wave), KB=64.
// RoPE applied to Q at fragment load (8 sincosf/thread once per block —
// replaces a whole 64MB rope dispatch). Q pre-scaled by scale*log2e in its
// GEMM epilogue -> softmax in exp2 domain. Swapped QK^T; P in registers
// (cvt_pkrtz + permlane, named scalars). K and V double-buffered,
// counted-vmcnt pipeline (no drain in steady loop). XCD-grouped blocks.
// ---------------------------------------------------------------------------
#define QB 128
#define KB 64
#define THR2 11.541561f  // 8 * log2(e)

__global__ __launch_bounds__(256, 2)
void flash_attn(const _Float16* __restrict__ qg, const _Float16* __restrict__ kg,
                const _Float16* __restrict__ vt, _Float16* __restrict__ og,
                FreqT ft, int Bn, int Hn, int Sn) {
  const int D = 128;
  const int E = Hn * D;

  __shared__ _Float16 Ksh[2][KB * 128];   // swizzled, 2 x 16KB
  __shared__ _Float16 Vsh[2][D * KB];     // V^T tiles, swizzled, 2 x 16KB
  __shared__ float sm[4][32];             // per-wave stat broadcast

  int qtiles = Sn / QB;                   // 16
  int nwg = gridDim.x;
  int bid = blockIdx.x;
  int swzb = (bid & 7) * (nwg >> 3) + (bid >> 3);  // XCD-grouped
  int bh = swzb / qtiles, qt = swzb % qtiles;
  int b = bh / Hn, h = bh % Hn;

  int tid = threadIdx.x, lane = tid & 63, w = tid >> 6;
  int g = lane >> 4, lc = lane & 15;
  int lc7 = lc & 7;

  const size_t headoff = ((size_t)b * Sn) * E + (size_t)h * D;
  const _Float16* qp = qg + headoff;
  const _Float16* kp = kg + headoff;
  const _Float16* vtp = vt + (size_t)(b * Hn + h) * D * Sn;  // [d][s]

  // Q fragments (B-operand: Q[q=mf*16+lc][k]) — pre-scaled by s*log2e in
  // GEMM; apply RoPE here (one freq-group per fragment: fi = kf*4+g).
  int q0 = qt * QB + w * 32;
  half8 aq[2][4];
#pragma unroll
  for (int mf = 0; mf < 2; ++mf) {
    int srow = q0 + mf * 16 + lc;
#pragma unroll
    for (int kf = 0; kf < 4; ++kf) {
      half8 v = *(const half8*)(qp + (size_t)srow * E + kf * 32 + g * 8);
      float fr = ft.f[kf * 4 + g];
      float sv, cv;
      sincosf((float)srow * fr, &sv, &cv);
      half8 r;
#pragma unroll
      for (int p = 0; p < 4; ++p) {
        float x1 = (float)v[2 * p], x2 = (float)v[2 * p + 1];
        r[2 * p] = (_Float16)(x1 * cv - x2 * sv);
        r[2 * p + 1] = (_Float16)(x1 * sv + x2 * cv);
      }
      aq[mf][kf] = r;
    }
  }

  float mrun[2] = {-1e30f, -1e30f}, lpart[2] = {0.f, 0.f};
  f32x4 o[2][8] = {};

  // K staging: 4 rows/call, pre-swizzled source col
  int krow = 4 * w + (lane >> 4);
  int kcol = ((lane & 15) ^ (krow & 7)) * 8;
  const _Float16* gK = kp + (size_t)krow * E + kcol;
  // V^T staging: 8 rows/call, pre-swizzled source col
  int vrow = w * 32 + (lane >> 3);
  int vcol = ((lane & 7) ^ (vrow & 7)) * 8;
  const _Float16* gV = vtp + (size_t)vrow * Sn + vcol;

  float* smw = sm[w];

  const int NT = Sn / KB;

#define STAGE_K(buf, kt) do {                                          \
    _Float16* lK_ = Ksh[buf] + w * 512;                                \
    _Pragma("unroll")                                                  \
    for (int i_ = 0; i_ < 4; ++i_)                                     \
      gload_lds16(gK + (size_t)((kt) * KB + 16 * i_) * E, lK_ + i_ * 2048); \
  } while (0)
#define STAGE_V(buf, kt) do {                                          \
    _Float16* lV_ = Vsh[buf] + w * 2048;                               \
    _Pragma("unroll")                                                  \
    for (int p_ = 0; p_ < 4; ++p_)                                     \
      gload_lds16(gV + (size_t)(p_ * 8) * Sn + (kt) * KB, lV_ + p_ * 512); \
  } while (0)

  // prologue: K(0), K(1), V(0) in flight; wait only K(0)
  STAGE_K(0, 0);
  STAGE_K(1, 1);
  STAGE_V(0, 0);
  WAIT_VM8();
  S_BARRIER();

  for (int t = 0; t < NT; ++t) {
    int c = t & 1;

    // QK^T swapped on Ksh[c]: per lane q = mf*16+lc, kv = nf*16+g*4+j
    f32x4 st[2][4] = {};
    {
      const _Float16* Kc = Ksh[c];
      __builtin_amdgcn_s_setprio(1);
#pragma unroll
      for (int kf = 0; kf < 4; ++kf) {
        half8 bk[4];
#pragma unroll
        for (int nf = 0; nf < 4; ++nf)
          bk[nf] = *(const half8*)&Kc[(nf * 16 + lc) * 128 + (((kf * 4 + g) ^ lc7) << 3)];
#pragma unroll
        for (int nf = 0; nf < 4; ++nf)
#pragma unroll
          for (int mf = 0; mf < 2; ++mf)
            st[mf][nf] = mfma16(bk[nf], aq[mf][kf], st[mf][nf]);
      }
      __builtin_amdgcn_s_setprio(0);
    }
    WAIT_LGKM0();
    S_BARRIER();  // all waves done reading Ksh[c] (and prior PV's Vsh)

    // issue next-tile stages into just-freed buffers (stay in flight)
    if (t + 1 < NT) STAGE_V(c ^ 1, t + 1);
    if (t + 2 < NT) STAGE_K(c, t + 2);

    // softmax in exp2 domain, defer-max
    bool resc[2];
#pragma unroll
    for (int mf = 0; mf < 2; ++mf) {
      f32x4 m4 = st[mf][0];
#pragma unroll
      for (int nf = 1; nf < 4; ++nf)
#pragma unroll
        for (int j = 0; j < 4; ++j) m4[j] = fmaxf(m4[j], st[mf][nf][j]);
      float mx = fmaxf(fmaxf(m4[0], m4[1]), fmaxf(m4[2], m4[3]));
      mx = fmaxf(mx, __shfl_xor(mx, 16));
      mx = fmaxf(mx, __shfl_xor(mx, 32));
      resc[mf] = __any(mx > mrun[mf] + THR2);
      if (resc[mf]) {
        float mnew = fmaxf(mrun[mf], mx);
        float r = __builtin_amdgcn_exp2f(mrun[mf] - mnew);
        mrun[mf] = mnew;
        lpart[mf] *= r;
        if (g == 0) smw[mf * 16 + lc] = r;
      }
    }
#pragma unroll
    for (int mf = 0; mf < 2; ++mf)
      if (resc[mf]) {
        f32x4 rv = *(const f32x4*)&smw[mf * 16 + g * 4];
#pragma unroll
        for (int df = 0; df < 8; ++df)
#pragma unroll
          for (int j = 0; j < 4; ++j) o[mf][df][j] *= rv[j];
      }

    // P = exp2(st - m), pack + permlane dance. Named scalars only.
    half8 pa00, pa01, pa10, pa11;  // pa<mf><kk>
#define PACK_P(MF, PA0, PA1) do {                                          \
      float e0, e1;                                                        \
      e0 = __builtin_amdgcn_exp2f(st[MF][0][0] - mrun[MF]);                \
      e1 = __builtin_amdgcn_exp2f(st[MF][0][1] - mrun[MF]);                \
      lpart[MF] += e0 + e1; unsigned k00 = pk_f16(e0, e1);                 \
      e0 = __builtin_amdgcn_exp2f(st[MF][0][2] - mrun[MF]);                \
      e1 = __builtin_amdgcn_exp2f(st[MF][0][3] - mrun[MF]);                \
      lpart[MF] += e0 + e1; unsigned k01 = pk_f16(e0, e1);                 \
      e0 = __builtin_amdgcn_exp2f(st[MF][1][0] - mrun[MF]);                \
      e1 = __builtin_amdgcn_exp2f(st[MF][1][1] - mrun[MF]);                \
      lpart[MF] += e0 + e1; unsigned k10 = pk_f16(e0, e1);                 \
      e0 = __builtin_amdgcn_exp2f(st[MF][1][2] - mrun[MF]);                \
      e1 = __builtin_amdgcn_exp2f(st[MF][1][3] - mrun[MF]);                \
      lpart[MF] += e0 + e1; unsigned k11 = pk_f16(e0, e1);                 \
      e0 = __builtin_amdgcn_exp2f(st[MF][2][0] - mrun[MF]);                \
      e1 = __builtin_amdgcn_exp2f(st[MF][2][1] - mrun[MF]);                \
      lpart[MF] += e0 + e1; unsigned k20 = pk_f16(e0, e1);                 \
      e0 = __builtin_amdgcn_exp2f(st[MF][2][2] - mrun[MF]);                \
      e1 = __builtin_amdgcn_exp2f(st[MF][2][3] - mrun[MF]);                \
      lpart[MF] += e0 + e1; unsigned k21 = pk_f16(e0, e1);                 \
      e0 = __builtin_amdgcn_exp2f(st[MF][3][0] - mrun[MF]);                \
      e1 = __builtin_amdgcn_exp2f(st[MF][3][1] - mrun[MF]);                \
      lpart[MF] += e0 + e1; unsigned k30 = pk_f16(e0, e1);                 \
      e0 = __builtin_amdgcn_exp2f(st[MF][3][2] - mrun[MF]);                \
      e1 = __builtin_amdgcn_exp2f(st[MF][3][3] - mrun[MF]);                \
      lpart[MF] += e0 + e1; unsigned k31 = pk_f16(e0, e1);                 \
      asm("v_permlane32_swap_b32 %0, %1" : "+v"(k00), "+v"(k10));          \
      asm("v_permlane16_swap_b32 %0, %1" : "+v"(k00), "+v"(k10));          \
      asm("v_permlane32_swap_b32 %0, %1" : "+v"(k01), "+v"(k11));          \
      asm("v_permlane16_swap_b32 %0, %1" : "+v"(k01), "+v"(k11));          \
      asm("v_permlane32_swap_b32 %0, %1" : "+v"(k20), "+v"(k30));          \
      asm("v_permlane16_swap_b32 %0, %1" : "+v"(k20), "+v"(k30));          \
      asm("v_permlane32_swap_b32 %0, %1" : "+v"(k21), "+v"(k31));          \
      asm("v_permlane16_swap_b32 %0, %1" : "+v"(k21), "+v"(k31));          \
      uint4v p0v, p1v;                                                     \
      p0v[0] = k00; p0v[1] = k01; p0v[2] = k10; p0v[3] = k11;              \
      p1v[0] = k20; p1v[1] = k21; p1v[2] = k30; p1v[3] = k31;              \
      PA0 = __builtin_bit_cast(half8, p0v);                                \
      PA1 = __builtin_bit_cast(half8, p1v);                                \
    } while (0)
    PACK_P(0, pa00, pa01);
    PACK_P(1, pa10, pa11);
#undef PACK_P

    // retire exactly V(t) + K(t+1); newer stages stay in flight
    if (t + 2 < NT) { WAIT_VM8(); }
    else if (t + 1 < NT) { WAIT_VM4(); }
    else { WAIT_VM0(); }
    S_BARRIER();  // all waves' V(t) landed

    // PV: O[32,128] += P[32,64] @ V[64,128]  (P from registers)
    __builtin_amdgcn_s_setprio(1);
    {
      const _Float16* Vc = Vsh[c];
      int csw0 = (g ^ lc7) << 3;
      int csw1 = ((4 + g) ^ lc7) << 3;
#pragma unroll
      for (int df = 0; df < 8; ++df) {
        half8 bv0 = *(const half8*)&Vc[(df * 16 + lc) * 64 + csw0];
        o[0][df] = mfma16(pa00, bv0, o[0][df]);
        o[1][df] = mfma16(pa10, bv0, o[1][df]);
      }
#pragma unroll
      for (int df = 0; df < 8; ++df) {
        half8 bv1 = *(const half8*)&Vc[(df * 16 + lc) * 64 + csw1];
        o[0][df] = mfma16(pa01, bv1, o[0][df]);
        o[1][df] = mfma16(pa11, bv1, o[1][df]);
      }
    }
    __builtin_amdgcn_s_setprio(0);
  }
#undef STAGE_K
#undef STAGE_V

  // epilogue: final l across g-groups, broadcast 1/l, normalize, write
#pragma unroll
  for (int mf = 0; mf < 2; ++mf) {
    float l = lpart[mf];
    l += __shfl_xor(l, 16);
    l += __shfl_xor(l, 32);
    if (g == 0) smw[mf * 16 + lc] = 1.0f / l;
  }
  _Float16* op = og + headoff;
#pragma unroll
  for (int mf = 0; mf < 2; ++mf) {
    f32x4 li = *(const f32x4*)&smw[mf * 16 + g * 4];
#pragma unroll
    for (int j = 0; j < 4; ++j) {
      int row = q0 + mf * 16 + g * 4 + j;
#pragma unroll
      for (int df = 0; df < 8; ++df)
        op[(size_t)row * E + df * 16 + lc] = (_Float16)(o[mf][df][j] * li[j]);
    }
  }
}

// ---------------------------------------------------------------------------
// Launch
// ---------------------------------------------------------------------------
extern "C" void kernel_launch(void* const* d_in, const int* in_sizes, int n_in,
                              void* d_out, int out_size, void* d_ws, size_t ws_size,
                              hipStream_t stream) {
  const float* x  = (const float*)d_in[0];
  const float* Wq = (const float*)d_in[1];
  const float* bq = (const float*)d_in[2];
  const float* Wk = (const float*)d_in[3];
  const float* bk = (const float*)d_in[4];
  const float* Wv = (const float*)d_in[5];
  const float* bv = (const float*)d_in[6];
  const float* Wo = (const float*)d_in[7];
  const float* bo = (const float*)d_in[8];

  const int E = in_sizes[2];        // 4096
  const int M = in_sizes[0] / E;    // B*S = 4096
  const int S = 2048;
  const int Bb = M / S;             // 2
  const int H = 32;

  _Float16* xh = (_Float16*)d_ws;               // M*E (reused as attn-out)
  _Float16* wh = xh + (size_t)M * E;            // E*E (W casts; then V^T)
  _Float16* qh = wh + (size_t)E * E;            // M*E
  _Float16* kh = qh + (size_t)M * E;
  _Float16* vh = kh + (size_t)M * E;
  _Float16* oh = xh;
  _Float16* vtb = wh;                           // V^T lives in wh during attn

  FreqT ft;
  for (int j = 0; j < 16; ++j) {
    float pf = (float)pow(10000.0, (double)(2 * j));  // inf for j>=5 (faithful)
    ft.f[j] = 1.0f / (pf / 32.0f);
  }

  // Q pre-scale: 1/sqrt(128) * log2(e)  (softmax runs in exp2 domain)
  const float qs = 0.08838834764831845f * 1.4426950408889634f;

  long nx8 = (long)M * E / 8;
  long nw8 = (long)E * E / 8;
  dim3 blk(256);
  int cb_x = (int)((nx8 + 255) / 256);
  int cb_w = (int)((nw8 + 255) / 256);
  int gemm_grid = (M / GBM) * (E / GBN);  // 256

  cast_f32_f16<<<cb_x, blk, 0, stream>>>(x, xh, nx8);

  cast_f32_f16<<<cb_w, blk, 0, stream>>>(Wq, wh, nw8);
  gemm256<_Float16><<<gemm_grid, 512, 0, stream>>>(xh, wh, bq, qh, M, E, E, qs);
  cast_f32_f16<<<cb_w, blk, 0, stream>>>(Wk, wh, nw8);
  gemm256<_Float16><<<gemm_grid, 512, 0, stream>>>(xh, wh, bk, kh, M, E, E, 1.0f);
  cast_f32_f16<<<cb_w, blk, 0, stream>>>(Wv, wh, nw8);
  gemm256<_Float16><<<gemm_grid, 512, 0, stream>>>(xh, wh, bv, vh, M, E, E, 1.0f);

  rope_kernel<<<cb_x, blk, 0, stream>>>(kh, ft, S, E, nx8);

  transpose_v<<<Bb * H * (S / 64), blk, 0, stream>>>(vh, vtb, H, S);

  flash_attn<<<Bb * H * (S / QB), blk, 0, stream>>>(qh, kh, vtb, oh, ft, Bb, H, S);

  cast_f32_f16<<<cb_w, blk, 0, stream>>>(Wo, wh, nw8);
  gemm256<float><<<gemm_grid, 512, 0, stream>>>(oh, wh, bo, (float*)d_out, M, E, E, 1.0f);
}

// Round 15
// 755.189 us; speedup vs baseline: 1.0225x; 1.0154x over previous
//
#include <hip/hip_runtime.h>
#include <math.h>

// ---------------------------------------------------------------------------
// Types
// ---------------------------------------------------------------------------
typedef _Float16 half8 __attribute__((ext_vector_type(8)));
typedef _Float16 half4 __attribute__((ext_vector_type(4)));
typedef __fp16 fp16x2 __attribute__((ext_vector_type(2)));
typedef float f32x4 __attribute__((ext_vector_type(4)));
typedef unsigned uint4v __attribute__((ext_vector_type(4)));

struct FreqT { float f[16]; };

__device__ __forceinline__ f32x4 mfma16(half8 a, half8 b, f32x4 c) {
  return __builtin_amdgcn_mfma_f32_16x16x32_f16(a, b, c, 0, 0, 0);
}

__device__ __forceinline__ void gload_lds16(const void* g, void* l) {
  __builtin_amdgcn_global_load_lds(
      (const __attribute__((address_space(1))) void*)g,
      (__attribute__((address_space(3))) void*)l, 16, 0, 0);
}

__device__ __forceinline__ unsigned pk_f16(float p0, float p1) {
  fp16x2 h = __builtin_amdgcn_cvt_pkrtz(p0, p1);
  return __builtin_bit_cast(unsigned, h);
}

#define S_BARRIER() __builtin_amdgcn_s_barrier()
#define WAIT_LGKM0() asm volatile("s_waitcnt lgkmcnt(0)" ::: "memory")
#define WAIT_VM8() asm volatile("s_waitcnt vmcnt(8)" ::: "memory")
#define WAIT_VM4() asm volatile("s_waitcnt vmcnt(4)" ::: "memory")
#define WAIT_VM0() asm volatile("s_waitcnt vmcnt(0)" ::: "memory")

// ---------------------------------------------------------------------------
// Cast fp32 -> fp16, 8 elems/thread
// ---------------------------------------------------------------------------
__global__ __launch_bounds__(256)
void cast_f32_f16(const float* __restrict__ in, _Float16* __restrict__ out, long n8) {
  long i = (long)blockIdx.x * blockDim.x + threadIdx.x;
  if (i >= n8) return;
  float4 a = ((const float4*)in)[2 * i];
  float4 b = ((const float4*)in)[2 * i + 1];
  half8 v;
  v[0] = (_Float16)a.x; v[1] = (_Float16)a.y; v[2] = (_Float16)a.z; v[3] = (_Float16)a.w;
  v[4] = (_Float16)b.x; v[5] = (_Float16)b.y; v[6] = (_Float16)b.z; v[7] = (_Float16)b.w;
  ((half8*)out)[i] = v;
}

// ---------------------------------------------------------------------------
// GEMM 256x256x64, 8 waves (2M x 4N), 2-phase counted-vmcnt pipeline.
// C = (A @ W^T + bias) * smul.
// ---------------------------------------------------------------------------
#define GBM 256
#define GBN 256
#define GBK 64

template <typename OutT>
__global__ __launch_bounds__(512, 2)
void gemm256(const _Float16* __restrict__ A, const _Float16* __restrict__ W,
             const float* __restrict__ bias, OutT* __restrict__ C,
             int M, int N, int K, float smul) {
  __shared__ __align__(16) _Float16 lds[4][GBM * GBK];

  int nwg = gridDim.x;
  int bid = blockIdx.x;
  int cpx = nwg >> 3;
  int swz = (bid & 7) * cpx + (bid >> 3);
  int ntn = N / GBN;
  int m0 = (swz / ntn) * GBM, n0 = (swz % ntn) * GBN;

  int tid = threadIdx.x, lane = tid & 63, w = tid >> 6;
  int wm = w >> 2, wn = w & 3;
  int g = lane >> 4, lc = lane & 15;

  int r8 = w * 8 + (lane >> 3);
  int cs = (((lane & 7) ^ (lane >> 3)) << 3);
  const _Float16* gA = A + (size_t)(m0 + r8) * K + cs;
  const _Float16* gB = W + (size_t)(n0 + r8) * K + cs;

#define STAGE(bi, k0) do {                                            \
    _Float16* la_ = &lds[(bi) * 2][0] + w * 512;                      \
    _Float16* lb_ = &lds[(bi) * 2 + 1][0] + w * 512;                  \
    _Pragma("unroll")                                                 \
    for (int i_ = 0; i_ < 4; ++i_) {                                  \
      gload_lds16(gA + (size_t)(i_ * 64) * K + (k0), la_ + i_ * 4096);\
      gload_lds16(gB + (size_t)(i_ * 64) * K + (k0), lb_ + i_ * 4096);\
    } } while (0)

  int aOff[8], bOff[4];
#pragma unroll
  for (int mf = 0; mf < 8; ++mf) aOff[mf] = (wm * 128 + mf * 16 + lc) * 64;
#pragma unroll
  for (int nf = 0; nf < 4; ++nf) bOff[nf] = (wn * 64 + nf * 16 + lc) * 64;
  int co0 = ((g ^ (lc & 7)) << 3);
  int co1 = (((4 + g) ^ (lc & 7)) << 3);

  half8 a0[8], a1[8], b0[4], b1[4];
  f32x4 acc[8][4] = {};

#define LOAD_SET0(bi) do {                                            \
    const _Float16* lA_ = &lds[(bi) * 2][0];                          \
    const _Float16* lB_ = &lds[(bi) * 2 + 1][0];                      \
    _Pragma("unroll")                                                 \
    for (int mf = 0; mf < 4; ++mf) {                                  \
      a0[mf * 2 + 0] = *(const half8*)&lA_[aOff[mf] + co0];           \
      a0[mf * 2 + 1] = *(const half8*)&lA_[aOff[mf] + co1];           \
    }                                                                 \
    _Pragma("unroll")                                                 \
    for (int nf = 0; nf < 2; ++nf) {                                  \
      b0[nf * 2 + 0] = *(const half8*)&lB_[bOff[nf] + co0];           \
      b0[nf * 2 + 1] = *(const half8*)&lB_[bOff[nf] + co1];           \
    } } while (0)

#define LOAD_SET1(bi) do {                                            \
    const _Float16* lA_ = &lds[(bi) * 2][0];                          \
    const _Float16* lB_ = &lds[(bi) * 2 + 1][0];                      \
    _Pragma("unroll")                                                 \
    for (int mf = 0; mf < 4; ++mf) {                                  \
      a1[mf * 2 + 0] = *(const half8*)&lA_[aOff[mf + 4] + co0];       \
      a1[mf * 2 + 1] = *(const half8*)&lA_[aOff[mf + 4] + co1];       \
    }                                                                 \
    _Pragma("unroll")                                                 \
    for (int nf = 0; nf < 2; ++nf) {                                  \
      b1[nf * 2 + 0] = *(const half8*)&lB_[bOff[nf + 2] + co0];       \
      b1[nf * 2 + 1] = *(const half8*)&lB_[bOff[nf + 2] + co1];       \
    } } while (0)

#define MFMA_Q(mq, nq, ar, br) do {                                   \
    __builtin_amdgcn_s_setprio(1);                                    \
    _Pragma("unroll")                                                 \
    for (int mf = 0; mf < 4; ++mf)                                    \
      _Pragma("unroll")                                               \
      for (int nf = 0; nf < 2; ++nf)                                  \
        _Pragma("unroll")                                             \
        for (int kk = 0; kk < 2; ++kk)                                \
          acc[(mq) * 4 + mf][(nq) * 2 + nf] =                         \
              mfma16(ar[mf * 2 + kk], br[nf * 2 + kk],                \
                     acc[(mq) * 4 + mf][(nq) * 2 + nf]);              \
    __builtin_amdgcn_s_setprio(0); } while (0)

  const int NT = K >> 6;

  STAGE(0, 0);
  STAGE(1, GBK);
  WAIT_VM8();
  S_BARRIER();
  LOAD_SET0(0);

  for (int t = 0; t < NT - 2; ++t) {
    int cur = t & 1;
    LOAD_SET1(cur);
    MFMA_Q(0, 0, a0, b0);
    MFMA_Q(0, 1, a0, b1);
    WAIT_LGKM0();
    S_BARRIER();
    STAGE(cur, (t + 2) << 6);
    MFMA_Q(1, 1, a1, b1);
    MFMA_Q(1, 0, a1, b0);
    WAIT_VM8();
    S_BARRIER();
    LOAD_SET0(cur ^ 1);
  }
  {
    int cur = (NT - 2) & 1;
    LOAD_SET1(cur);
    MFMA_Q(0, 0, a0, b0);
    MFMA_Q(0, 1, a0, b1);
    MFMA_Q(1, 1, a1, b1);
    MFMA_Q(1, 0, a1, b0);
    WAIT_VM0();
    S_BARRIER();
    LOAD_SET0(cur ^ 1);
  }
  {
    LOAD_SET1((NT - 1) & 1);
    MFMA_Q(0, 0, a0, b0);
    MFMA_Q(0, 1, a0, b1);
    MFMA_Q(1, 1, a1, b1);
    MFMA_Q(1, 0, a1, b0);
  }

  int crow = m0 + wm * 128 + g * 4;
  int ccol = n0 + wn * 64 + lc;
#pragma unroll
  for (int nf = 0; nf < 4; ++nf) {
    float bv = bias[ccol + nf * 16];
#pragma unroll
    for (int mf = 0; mf < 8; ++mf)
#pragma unroll
      for (int j = 0; j < 4; ++j)
        C[(size_t)(crow + mf * 16 + j) * N + ccol + nf * 16] =
            (OutT)((acc[mf][nf][j] + bv) * smul);
  }
#undef STAGE
#undef LOAD_SET0
#undef LOAD_SET1
#undef MFMA_Q
}

// ---------------------------------------------------------------------------
// Sparse RoPE for K: only freq-group 0 (first 8 dims of each 128-dim head)
// has a non-negligible angle (f[0]=32; f[1..4]<=3.2e-7 -> below fp16
// resolution; f[5..15] == 0 exactly). 1/16 of the traffic of a full pass.
// ---------------------------------------------------------------------------
__global__ __launch_bounds__(256)
void rope_k0(_Float16* __restrict__ x, int Sn, int E, long n) {
  long i = (long)blockIdx.x * blockDim.x + threadIdx.x;
  if (i >= n) return;
  int gpr = E >> 7;                 // 128-dim heads per row
  int gi = (int)(i % gpr);
  long row = i / gpr;
  int s = (int)(row % Sn);
  float sv, cv;
  sincosf((float)s * 32.0f, &sv, &cv);
  _Float16* p = x + row * E + (size_t)gi * 128;
  half8 v = *(const half8*)p;
  half8 o;
#pragma unroll
  for (int q = 0; q < 4; ++q) {
    float x1 = (float)v[2 * q], x2 = (float)v[2 * q + 1];
    o[2 * q] = (_Float16)(x1 * cv - x2 * sv);
    o[2 * q + 1] = (_Float16)(x1 * sv + x2 * cv);
  }
  *(half8*)p = o;
}

// ---------------------------------------------------------------------------
// V transpose: vh [B,S,H*D] -> vt [B,H,D,S]
// ---------------------------------------------------------------------------
__global__ __launch_bounds__(256)
void transpose_v(const _Float16* __restrict__ v, _Float16* __restrict__ vt,
                 int Hn, int Sn) {
  const int D = 128;
  const int E = Hn * D;
  __shared__ _Float16 t[64][130];
  int spb = Sn / 64;
  int bid = blockIdx.x;
  int s0 = (bid % spb) * 64;
  int bh = bid / spb;
  int b = bh / Hn, h = bh % Hn;
  int tid = threadIdx.x;
  int r = tid >> 2, dc = (tid & 3) * 32;
  const _Float16* src = v + (size_t)(b * Sn + s0 + r) * E + h * D + dc;
#pragma unroll
  for (int i = 0; i < 4; ++i) {
    half8 x = *(const half8*)(src + i * 8);
#pragma unroll
    for (int k = 0; k < 4; ++k) {
      _Float16 a0 = x[2 * k], a1 = x[2 * k + 1];
      t[r][dc + i * 8 + 2 * k] = a0;
      t[r][dc + i * 8 + 2 * k + 1] = a1;
    }
  }
  __syncthreads();
  int d = tid >> 1, sh = (tid & 1) * 32;
  half8 ov[4];
#pragma unroll
  for (int c = 0; c < 4; ++c)
#pragma unroll
    for (int j = 0; j < 8; ++j)
      ov[c][j] = t[sh + c * 8 + j][d];
  _Float16* dst = vt + ((size_t)bh * D + d) * Sn + s0 + sh;
#pragma unroll
  for (int c = 0; c < 4; ++c)
    *(half8*)(dst + c * 8) = ov[c];
}

// ---------------------------------------------------------------------------
// Flash attention (non-causal), D=128, 4 waves, QB=128 (32 q/wave), KB=64.
// Q-RoPE fused at fragment load, exploiting degenerate freqs: only the
// (kf==0, g==0) lanes run a real sincosf (2 exec-masked calls/thread);
// g=1..3 use first-order rotation; kf>=1 fragments are identity.
// Q pre-scaled by scale*log2e in GEMM -> exp2-domain softmax. Swapped
// QK^T; P in registers (cvt_pkrtz + permlane, named scalars). K and V
// double-buffered, counted-vmcnt pipeline. XCD-grouped blocks.
// ---------------------------------------------------------------------------
#define QB 128
#define KB 64
#define THR2 11.541561f  // 8 * log2(e)

__global__ __launch_bounds__(256, 2)
void flash_attn(const _Float16* __restrict__ qg, const _Float16* __restrict__ kg,
                const _Float16* __restrict__ vt, _Float16* __restrict__ og,
                FreqT ft, int Bn, int Hn, int Sn) {
  const int D = 128;
  const int E = Hn * D;

  __shared__ _Float16 Ksh[2][KB * 128];   // swizzled, 2 x 16KB
  __shared__ _Float16 Vsh[2][D * KB];     // V^T tiles, swizzled, 2 x 16KB
  __shared__ float sm[4][32];             // per-wave stat broadcast

  int qtiles = Sn / QB;                   // 16
  int nwg = gridDim.x;
  int bid = blockIdx.x;
  int swzb = (bid & 7) * (nwg >> 3) + (bid >> 3);  // XCD-grouped
  int bh = swzb / qtiles, qt = swzb % qtiles;
  int b = bh / Hn, h = bh % Hn;

  int tid = threadIdx.x, lane = tid & 63, w = tid >> 6;
  int g = lane >> 4, lc = lane & 15;
  int lc7 = lc & 7;

  const size_t headoff = ((size_t)b * Sn) * E + (size_t)h * D;
  const _Float16* qp = qg + headoff;
  const _Float16* kp = kg + headoff;
  const _Float16* vtp = vt + (size_t)(b * Hn + h) * D * Sn;  // [d][s]

  // Q fragments (B-operand: Q[q=mf*16+lc][k]); rope on kf==0 only.
  int q0 = qt * QB + w * 32;
  half8 aq[2][4];
#pragma unroll
  for (int mf = 0; mf < 2; ++mf) {
    int srow = q0 + mf * 16 + lc;
    const _Float16* qrow = qp + (size_t)srow * E;
    {
      half8 v = *(const half8*)(qrow + g * 8);
      float sv, cv;
      if (g == 0) {
        sincosf((float)srow * 32.0f, &sv, &cv);
      } else {
        sv = (float)srow * ft.f[g];  // <= 6.5e-4: sin(x)=x, cos(x)=1
        cv = 1.0f;
      }
      half8 r;
#pragma unroll
      for (int p = 0; p < 4; ++p) {
        float x1 = (float)v[2 * p], x2 = (float)v[2 * p + 1];
        r[2 * p] = (_Float16)(x1 * cv - x2 * sv);
        r[2 * p + 1] = (_Float16)(x1 * sv + x2 * cv);
      }
      aq[mf][0] = r;
    }
#pragma unroll
    for (int kf = 1; kf < 4; ++kf)
      aq[mf][kf] = *(const half8*)(qrow + kf * 32 + g * 8);
  }

  float mrun[2] = {-1e30f, -1e30f}, lpart[2] = {0.f, 0.f};
  f32x4 o[2][8] = {};

  // K staging: 4 rows/call, pre-swizzled source col
  int krow = 4 * w + (lane >> 4);
  int kcol = ((lane & 15) ^ (krow & 7)) * 8;
  const _Float16* gK = kp + (size_t)krow * E + kcol;
  // V^T staging: 8 rows/call, pre-swizzled source col
  int vrow = w * 32 + (lane >> 3);
  int vcol = ((lane & 7) ^ (vrow & 7)) * 8;
  const _Float16* gV = vtp + (size_t)vrow * Sn + vcol;

  float* smw = sm[w];

  const int NT = Sn / KB;

#define STAGE_K(buf, kt) do {                                          \
    _Float16* lK_ = Ksh[buf] + w * 512;                                \
    _Pragma("unroll")                                                  \
    for (int i_ = 0; i_ < 4; ++i_)                                     \
      gload_lds16(gK + (size_t)((kt) * KB + 16 * i_) * E, lK_ + i_ * 2048); \
  } while (0)
#define STAGE_V(buf, kt) do {                                          \
    _Float16* lV_ = Vsh[buf] + w * 2048;                               \
    _Pragma("unroll")                                                  \
    for (int p_ = 0; p_ < 4; ++p_)                                     \
      gload_lds16(gV + (size_t)(p_ * 8) * Sn + (kt) * KB, lV_ + p_ * 512); \
  } while (0)

  // prologue: K(0), K(1), V(0) in flight; wait only K(0)
  STAGE_K(0, 0);
  STAGE_K(1, 1);
  STAGE_V(0, 0);
  WAIT_VM8();
  S_BARRIER();

  for (int t = 0; t < NT; ++t) {
    int c = t & 1;

    // QK^T swapped on Ksh[c]: per lane q = mf*16+lc, kv = nf*16+g*4+j
    f32x4 st[2][4] = {};
    {
      const _Float16* Kc = Ksh[c];
      __builtin_amdgcn_s_setprio(1);
#pragma unroll
      for (int kf = 0; kf < 4; ++kf) {
        half8 bk[4];
#pragma unroll
        for (int nf = 0; nf < 4; ++nf)
          bk[nf] = *(const half8*)&Kc[(nf * 16 + lc) * 128 + (((kf * 4 + g) ^ lc7) << 3)];
#pragma unroll
        for (int nf = 0; nf < 4; ++nf)
#pragma unroll
          for (int mf = 0; mf < 2; ++mf)
            st[mf][nf] = mfma16(bk[nf], aq[mf][kf], st[mf][nf]);
      }
      __builtin_amdgcn_s_setprio(0);
    }
    WAIT_LGKM0();
    S_BARRIER();  // all waves done reading Ksh[c] (and prior PV's Vsh)

    // issue next-tile stages into just-freed buffers (stay in flight)
    if (t + 1 < NT) STAGE_V(c ^ 1, t + 1);
    if (t + 2 < NT) STAGE_K(c, t + 2);

    // softmax in exp2 domain, defer-max
    bool resc[2];
#pragma unroll
    for (int mf = 0; mf < 2; ++mf) {
      f32x4 m4 = st[mf][0];
#pragma unroll
      for (int nf = 1; nf < 4; ++nf)
#pragma unroll
        for (int j = 0; j < 4; ++j) m4[j] = fmaxf(m4[j], st[mf][nf][j]);
      float mx = fmaxf(fmaxf(m4[0], m4[1]), fmaxf(m4[2], m4[3]));
      mx = fmaxf(mx, __shfl_xor(mx, 16));
      mx = fmaxf(mx, __shfl_xor(mx, 32));
      resc[mf] = __any(mx > mrun[mf] + THR2);
      if (resc[mf]) {
        float mnew = fmaxf(mrun[mf], mx);
        float r = __builtin_amdgcn_exp2f(mrun[mf] - mnew);
        mrun[mf] = mnew;
        lpart[mf] *= r;
        if (g == 0) smw[mf * 16 + lc] = r;
      }
    }
#pragma unroll
    for (int mf = 0; mf < 2; ++mf)
      if (resc[mf]) {
        f32x4 rv = *(const f32x4*)&smw[mf * 16 + g * 4];
#pragma unroll
        for (int df = 0; df < 8; ++df)
#pragma unroll
          for (int j = 0; j < 4; ++j) o[mf][df][j] *= rv[j];
      }

    // P = exp2(st - m), pack + permlane dance. Named scalars only.
    half8 pa00, pa01, pa10, pa11;  // pa<mf><kk>
#define PACK_P(MF, PA0, PA1) do {                                          \
      float e0, e1;                                                        \
      e0 = __builtin_amdgcn_exp2f(st[MF][0][0] - mrun[MF]);                \
      e1 = __builtin_amdgcn_exp2f(st[MF][0][1] - mrun[MF]);                \
      lpart[MF] += e0 + e1; unsigned k00 = pk_f16(e0, e1);                 \
      e0 = __builtin_amdgcn_exp2f(st[MF][0][2] - mrun[MF]);                \
      e1 = __builtin_amdgcn_exp2f(st[MF][0][3] - mrun[MF]);                \
      lpart[MF] += e0 + e1; unsigned k01 = pk_f16(e0, e1);                 \
      e0 = __builtin_amdgcn_exp2f(st[MF][1][0] - mrun[MF]);                \
      e1 = __builtin_amdgcn_exp2f(st[MF][1][1] - mrun[MF]);                \
      lpart[MF] += e0 + e1; unsigned k10 = pk_f16(e0, e1);                 \
      e0 = __builtin_amdgcn_exp2f(st[MF][1][2] - mrun[MF]);                \
      e1 = __builtin_amdgcn_exp2f(st[MF][1][3] - mrun[MF]);                \
      lpart[MF] += e0 + e1; unsigned k11 = pk_f16(e0, e1);                 \
      e0 = __builtin_amdgcn_exp2f(st[MF][2][0] - mrun[MF]);                \
      e1 = __builtin_amdgcn_exp2f(st[MF][2][1] - mrun[MF]);                \
      lpart[MF] += e0 + e1; unsigned k20 = pk_f16(e0, e1);                 \
      e0 = __builtin_amdgcn_exp2f(st[MF][2][2] - mrun[MF]);                \
      e1 = __builtin_amdgcn_exp2f(st[MF][2][3] - mrun[MF]);                \
      lpart[MF] += e0 + e1; unsigned k21 = pk_f16(e0, e1);                 \
      e0 = __builtin_amdgcn_exp2f(st[MF][3][0] - mrun[MF]);                \
      e1 = __builtin_amdgcn_exp2f(st[MF][3][1] - mrun[MF]);                \
      lpart[MF] += e0 + e1; unsigned k30 = pk_f16(e0, e1);                 \
      e0 = __builtin_amdgcn_exp2f(st[MF][3][2] - mrun[MF]);                \
      e1 = __builtin_amdgcn_exp2f(st[MF][3][3] - mrun[MF]);                \
      lpart[MF] += e0 + e1; unsigned k31 = pk_f16(e0, e1);                 \
      asm("v_permlane32_swap_b32 %0, %1" : "+v"(k00), "+v"(k10));          \
      asm("v_permlane16_swap_b32 %0, %1" : "+v"(k00), "+v"(k10));          \
      asm("v_permlane32_swap_b32 %0, %1" : "+v"(k01), "+v"(k11));          \
      asm("v_permlane16_swap_b32 %0, %1" : "+v"(k01), "+v"(k11));          \
      asm("v_permlane32_swap_b32 %0, %1" : "+v"(k20), "+v"(k30));          \
      asm("v_permlane16_swap_b32 %0, %1" : "+v"(k20), "+v"(k30));          \
      asm("v_permlane32_swap_b32 %0, %1" : "+v"(k21), "+v"(k31));          \
      asm("v_permlane16_swap_b32 %0, %1" : "+v"(k21), "+v"(k31));          \
      uint4v p0v, p1v;                                                     \
      p0v[0] = k00; p0v[1] = k01; p0v[2] = k10; p0v[3] = k11;              \
      p1v[0] = k20; p1v[1] = k21; p1v[2] = k30; p1v[3] = k31;              \
      PA0 = __builtin_bit_cast(half8, p0v);                                \
      PA1 = __builtin_bit_cast(half8, p1v);                                \
    } while (0)
    PACK_P(0, pa00, pa01);
    PACK_P(1, pa10, pa11);
#undef PACK_P

    // retire exactly V(t) + K(t+1); newer stages stay in flight
    if (t + 2 < NT) { WAIT_VM8(); }
    else if (t + 1 < NT) { WAIT_VM4(); }
    else { WAIT_VM0(); }
    S_BARRIER();  // all waves' V(t) landed

    // PV: O[32,128] += P[32,64] @ V[64,128]  (P from registers)
    __builtin_amdgcn_s_setprio(1);
    {
      const _Float16* Vc = Vsh[c];
      int csw0 = (g ^ lc7) << 3;
      int csw1 = ((4 + g) ^ lc7) << 3;
#pragma unroll
      for (int df = 0; df < 8; ++df) {
        half8 bv0 = *(const half8*)&Vc[(df * 16 + lc) * 64 + csw0];
        o[0][df] = mfma16(pa00, bv0, o[0][df]);
        o[1][df] = mfma16(pa10, bv0, o[1][df]);
      }
#pragma unroll
      for (int df = 0; df < 8; ++df) {
        half8 bv1 = *(const half8*)&Vc[(df * 16 + lc) * 64 + csw1];
        o[0][df] = mfma16(pa01, bv1, o[0][df]);
        o[1][df] = mfma16(pa11, bv1, o[1][df]);
      }
    }
    __builtin_amdgcn_s_setprio(0);
  }
#undef STAGE_K
#undef STAGE_V

  // epilogue: final l across g-groups, broadcast 1/l, normalize, write
#pragma unroll
  for (int mf = 0; mf < 2; ++mf) {
    float l = lpart[mf];
    l += __shfl_xor(l, 16);
    l += __shfl_xor(l, 32);
    if (g == 0) smw[mf * 16 + lc] = 1.0f / l;
  }
  _Float16* op = og + headoff;
#pragma unroll
  for (int mf = 0; mf < 2; ++mf) {
    f32x4 li = *(const f32x4*)&smw[mf * 16 + g * 4];
#pragma unroll
    for (int j = 0; j < 4; ++j) {
      int row = q0 + mf * 16 + g * 4 + j;
#pragma unroll
      for (int df = 0; df < 8; ++df)
        op[(size_t)row * E + df * 16 + lc] = (_Float16)(o[mf][df][j] * li[j]);
    }
  }
}

// ---------------------------------------------------------------------------
// Launch
// ---------------------------------------------------------------------------
extern "C" void kernel_launch(void* const* d_in, const int* in_sizes, int n_in,
                              void* d_out, int out_size, void* d_ws, size_t ws_size,
                              hipStream_t stream) {
  const float* x  = (const float*)d_in[0];
  const float* Wq = (const float*)d_in[1];
  const float* bq = (const float*)d_in[2];
  const float* Wk = (const float*)d_in[3];
  const float* bk = (const float*)d_in[4];
  const float* Wv = (const float*)d_in[5];
  const float* bv = (const float*)d_in[6];
  const float* Wo = (const float*)d_in[7];
  const float* bo = (const float*)d_in[8];

  const int E = in_sizes[2];        // 4096
  const int M = in_sizes[0] / E;    // B*S = 4096
  const int S = 2048;
  const int Bb = M / S;             // 2
  const int H = 32;

  _Float16* xh = (_Float16*)d_ws;               // M*E (reused as attn-out)
  _Float16* wh = xh + (size_t)M * E;            // E*E (W casts; then V^T)
  _Float16* qh = wh + (size_t)E * E;            // M*E
  _Float16* kh = qh + (size_t)M * E;
  _Float16* vh = kh + (size_t)M * E;
  _Float16* oh = xh;
  _Float16* vtb = wh;                           // V^T lives in wh during attn

  FreqT ft;
  for (int j = 0; j < 16; ++j) {
    float pf = (float)pow(10000.0, (double)(2 * j));  // inf for j>=5 (faithful)
    ft.f[j] = 1.0f / (pf / 32.0f);
  }

  // Q pre-scale: 1/sqrt(128) * log2(e)  (softmax runs in exp2 domain)
  const float qs = 0.08838834764831845f * 1.4426950408889634f;

  long nx8 = (long)M * E / 8;
  long nw8 = (long)E * E / 8;
  dim3 blk(256);
  int cb_x = (int)((nx8 + 255) / 256);
  int cb_w = (int)((nw8 + 255) / 256);
  int gemm_grid = (M / GBM) * (E / GBN);  // 256

  cast_f32_f16<<<cb_x, blk, 0, stream>>>(x, xh, nx8);

  cast_f32_f16<<<cb_w, blk, 0, stream>>>(Wq, wh, nw8);
  gemm256<_Float16><<<gemm_grid, 512, 0, stream>>>(xh, wh, bq, qh, M, E, E, qs);
  cast_f32_f16<<<cb_w, blk, 0, stream>>>(Wk, wh, nw8);
  gemm256<_Float16><<<gemm_grid, 512, 0, stream>>>(xh, wh, bk, kh, M, E, E, 1.0f);
  cast_f32_f16<<<cb_w, blk, 0, stream>>>(Wv, wh, nw8);
  gemm256<_Float16><<<gemm_grid, 512, 0, stream>>>(xh, wh, bv, vh, M, E, E, 1.0f);

  // K rope: only freq-group 0 per head needs rotation (f[1..15] negligible/0)
  {
    long nk = (long)M * (E >> 7);   // one 8-elem group per head
    int cb_k = (int)((nk + 255) / 256);
    rope_k0<<<cb_k, blk, 0, stream>>>(kh, S, E, nk);
  }

  transpose_v<<<Bb * H * (S / 64), blk, 0, stream>>>(vh, vtb, H, S);

  flash_attn<<<Bb * H * (S / QB), blk, 0, stream>>>(qh, kh, vtb, oh, ft, Bb, H, S);

  cast_f32_f16<<<cb_w, blk, 0, stream>>>(Wo, wh, nw8);
  gemm256<float><<<gemm_grid, 512, 0, stream>>>(oh, wh, bo, (float*)d_out, M, E, E, 1.0f);
}